// Round 3
// baseline (899.194 us; speedup 1.0000x reference)
//
#include <hip/hip_runtime.h>

// Problem: B=2, S=2048, D=1024, H=16, hd=64. Output = (out [B,S,D] fp32, attn [B,H,S,S] fp32).
#define B_   2
#define S_   2048
#define D_   1024
#define H_   16
#define HD_  64
#define MTOT 4096  // B_*S_

typedef __bf16 bf16_t;
typedef bf16_t bf16x8 __attribute__((ext_vector_type(8)));
typedef bf16_t bf16x4 __attribute__((ext_vector_type(4)));
typedef float  f32x4  __attribute__((ext_vector_type(4)));

// ---------------- async global->LDS (16B per lane, wave-uniform LDS base) ----------------
__device__ __forceinline__ void gl_lds16(const bf16_t* g, bf16_t* l) {
  __builtin_amdgcn_global_load_lds((const __attribute__((address_space(1))) void*)g,
                                   (__attribute__((address_space(3))) void*)l, 16, 0, 0);
}

// ---------------- fp32 -> bf16 elementwise convert (x) ----------------
__global__ void cvt_kernel(const float* __restrict__ in, bf16_t* __restrict__ o) {
  size_t i = ((size_t)blockIdx.x * 256 + threadIdx.x) * 4;
  float4 v = *(const float4*)(in + i);
  bf16x4 p;
  p[0] = (bf16_t)v.x; p[1] = (bf16_t)v.y; p[2] = (bf16_t)v.z; p[3] = (bf16_t)v.w;
  *(bf16x4*)(o + i) = p;
}

// ---------------- weight transpose + convert: wT[n][k] = (bf16)w[k][n], 1024x1024 ----------------
__global__ void transpose_kernel(const float* __restrict__ w0, const float* __restrict__ w1,
                                 const float* __restrict__ w2, const float* __restrict__ w3,
                                 bf16_t* __restrict__ t0, bf16_t* __restrict__ t1,
                                 bf16_t* __restrict__ t2, bf16_t* __restrict__ t3) {
  const float* w = blockIdx.z == 0 ? w0 : (blockIdx.z == 1 ? w1 : (blockIdx.z == 2 ? w2 : w3));
  bf16_t*      o = blockIdx.z == 0 ? t0 : (blockIdx.z == 1 ? t1 : (blockIdx.z == 2 ? t2 : t3));
  __shared__ float tile[32][33];
  int bx = blockIdx.x * 32, by = blockIdx.y * 32;
#pragma unroll
  for (int i = threadIdx.y; i < 32; i += 8)
    tile[i][threadIdx.x] = w[(size_t)(by + i) * D_ + bx + threadIdx.x];
  __syncthreads();
#pragma unroll
  for (int i = threadIdx.y; i < 32; i += 8)
    o[(size_t)(bx + i) * D_ + by + threadIdx.x] = (bf16_t)tile[threadIdx.x][i];
}

// ---------------- shared GEMM core: 128x128 tile, BK=32, 4 waves each 64x64 ----------------
// A [M][1024] bf16 row-major, Bt [N][1024] bf16 row-major (Bt[n][k] = W[k][n]).
__device__ __forceinline__ void gemm_core(const bf16_t* __restrict__ A,
                                          const bf16_t* __restrict__ Bt,
                                          bf16_t* sA, bf16_t* sB,
                                          int bm, int bn, f32x4 acc[4][4]) {
  const int t = threadIdx.x;
  const int w = t >> 6, lane = t & 63;
  const int wr = w >> 1, wc = w & 1;
  const int r0 = w * 16 + (lane >> 2);   // staging row (0..63)
  const int kk = (lane & 3) * 8;         // staging k offset
  const int fr = lane & 15, fg = lane >> 4;

  for (int k0 = 0; k0 < 1024; k0 += 32) {
    __syncthreads();  // previous tile's ds_reads done
    gl_lds16(A  + (size_t)(bm + r0)      * 1024 + k0 + kk, sA + w * 512);
    gl_lds16(A  + (size_t)(bm + r0 + 64) * 1024 + k0 + kk, sA + 2048 + w * 512);
    gl_lds16(Bt + (size_t)(bn + r0)      * 1024 + k0 + kk, sB + w * 512);
    gl_lds16(Bt + (size_t)(bn + r0 + 64) * 1024 + k0 + kk, sB + 2048 + w * 512);
    __syncthreads();  // vmcnt(0) drained by barrier semantics
    bf16x8 a[4], b[4];
#pragma unroll
    for (int m = 0; m < 4; ++m)
      a[m] = *(const bf16x8*)&sA[(wr * 64 + m * 16 + fr) * 32 + fg * 8];
#pragma unroll
    for (int n = 0; n < 4; ++n)
      b[n] = *(const bf16x8*)&sB[(wc * 64 + n * 16 + fr) * 32 + fg * 8];
#pragma unroll
    for (int m = 0; m < 4; ++m)
#pragma unroll
      for (int n = 0; n < 4; ++n)
        acc[m][n] = __builtin_amdgcn_mfma_f32_16x16x32_bf16(a[m], b[n], acc[m][n], 0, 0, 0);
  }
}

// ---------------- fused QKV projection: z=0 -> Q, z=1 -> K, z=2 -> V(transposed) ----------------
// 1D grid 768 = 8 XCD chunks of 96; nid layout: z slowest, then bm, then bn.
__global__ __launch_bounds__(256) void qkv_gemm(
    const bf16_t* __restrict__ xb,
    const bf16_t* __restrict__ wqT, const bf16_t* __restrict__ wkT, const bf16_t* __restrict__ wvT,
    const float* __restrict__ bq, const float* __restrict__ bk, const float* __restrict__ bv,
    bf16_t* __restrict__ Qb, bf16_t* __restrict__ Kb, bf16_t* __restrict__ Vt) {
  __shared__ bf16_t sA[128 * 32], sB[128 * 32];
  const int bid = blockIdx.x;
  const int nid = (bid & 7) * 96 + (bid >> 3);   // bijective: 768 = 8*96
  const int z = nid >> 8, rem = nid & 255;
  const int bm = (rem >> 3) * 128, bn = (rem & 7) * 128;
  const bf16_t* Bt   = z == 0 ? wqT : (z == 1 ? wkT : wvT);
  const float*  bias = z == 0 ? bq  : (z == 1 ? bk  : bv);

  f32x4 acc[4][4];
#pragma unroll
  for (int m = 0; m < 4; ++m)
#pragma unroll
    for (int n = 0; n < 4; ++n) acc[m][n] = (f32x4){0.f, 0.f, 0.f, 0.f};

  gemm_core(xb, Bt, sA, sB, bm, bn, acc);

  const int t = threadIdx.x, w = t >> 6, lane = t & 63;
  const int wr = w >> 1, wc = w & 1, fr = lane & 15, fg = lane >> 4;
  if (z <= 1) {
    bf16_t* O = (z == 0) ? Qb : Kb;  // [b][h][s][d]
#pragma unroll
    for (int m = 0; m < 4; ++m)
#pragma unroll
      for (int n = 0; n < 4; ++n) {
        int col = bn + wc * 64 + n * 16 + fr;
        int h = col >> 6, d = col & 63;
        float bi = bias[col];
#pragma unroll
        for (int j = 0; j < 4; ++j) {
          int row = bm + wr * 64 + m * 16 + fg * 4 + j;
          int bb = row >> 11, s = row & 2047;
          O[(((size_t)(bb * H_ + h)) * S_ + s) * HD_ + d] = (bf16_t)(acc[m][n][j] + bi);
        }
      }
  } else {
    // Vt [b][h][d][s] : pack 4 consecutive s per lane
#pragma unroll
    for (int m = 0; m < 4; ++m)
#pragma unroll
      for (int n = 0; n < 4; ++n) {
        int col = bn + wc * 64 + n * 16 + fr;
        int h = col >> 6, d = col & 63;
        float bi = bias[col];
        int row0 = bm + wr * 64 + m * 16 + fg * 4;
        int bb = row0 >> 11, s0 = row0 & 2047;
        bf16x4 pk;
#pragma unroll
        for (int j = 0; j < 4; ++j) pk[j] = (bf16_t)(acc[m][n][j] + bi);
        *(bf16x4*)&Vt[(((size_t)(bb * H_ + h)) * HD_ + d) * S_ + s0] = pk;
      }
  }
}

// ---------------- output projection: out = Ob @ wo + bo (fp32 out) ----------------
// 1D grid 256 = 8 XCD chunks of 32.
__global__ __launch_bounds__(256) void out_gemm(const bf16_t* __restrict__ Ob,
                                                const bf16_t* __restrict__ woT,
                                                const float* __restrict__ bo,
                                                float* __restrict__ out) {
  __shared__ bf16_t sA[128 * 32], sB[128 * 32];
  const int bid = blockIdx.x;
  const int nid = (bid & 7) * 32 + (bid >> 3);   // bijective: 256 = 8*32
  const int bm = (nid >> 3) * 128, bn = (nid & 7) * 128;
  f32x4 acc[4][4];
#pragma unroll
  for (int m = 0; m < 4; ++m)
#pragma unroll
    for (int n = 0; n < 4; ++n) acc[m][n] = (f32x4){0.f, 0.f, 0.f, 0.f};

  gemm_core(Ob, woT, sA, sB, bm, bn, acc);

  const int t = threadIdx.x, w = t >> 6, lane = t & 63;
  const int wr = w >> 1, wc = w & 1, fr = lane & 15, fg = lane >> 4;
#pragma unroll
  for (int m = 0; m < 4; ++m)
#pragma unroll
    for (int n = 0; n < 4; ++n) {
      int col = bn + wc * 64 + n * 16 + fr;
      float bi = bo[col];
#pragma unroll
      for (int j = 0; j < 4; ++j) {
        int row = bm + wr * 64 + m * 16 + fg * 4 + j;
        __builtin_nontemporal_store(acc[m][n][j] + bi, &out[(size_t)row * D_ + col]);
      }
    }
}

// ---------------- fused attention: 2-pass softmax (no max shift; scores bounded), attn + Ob ----------------
// 1D grid 1024 = 8 XCD chunks of 128 (=4 heads each). Block 256 (4 independent waves x 16 q-rows).
__global__ __launch_bounds__(256) void attn_kernel(const bf16_t* __restrict__ Qb,
                                                   const bf16_t* __restrict__ Kb,
                                                   const bf16_t* __restrict__ Vt,
                                                   float* __restrict__ attn,
                                                   bf16_t* __restrict__ Ob) {
  __shared__ bf16_t p_lds[4][16 * 72];  // per-wave P tile, stride 72 (144B: 16B-mult, conflict-free read)
  const int t = threadIdx.x, w = t >> 6, lane = t & 63;
  const int fr = lane & 15, fg = lane >> 4;
  const int bid = blockIdx.x;
  const int nid = (bid & 7) * 128 + (bid >> 3);   // bijective XCD swizzle: 1024 = 8*128
  const int qblk = nid & 31, bh = nid >> 5;
  const int bb = bh >> 4, h = bh & 15;
  const int q0 = qblk * 64 + w * 16;  // this wave's q-row base within the head

  const bf16_t* Qh = Qb + (size_t)bh * S_ * HD_;
  const bf16_t* Kh = Kb + (size_t)bh * S_ * HD_;
  const bf16_t* Vh = Vt + (size_t)bh * HD_ * S_;

  // Q fragments (held in registers for both passes)
  bf16x8 aq0 = *(const bf16x8*)&Qh[(size_t)(q0 + fr) * HD_ + fg * 8];
  bf16x8 aq1 = *(const bf16x8*)&Qh[(size_t)(q0 + fr) * HD_ + 32 + fg * 8];

  // ---- pass 1: per-lane partial sum of exp(s) (no max shift: |s| <~ 8, exp fp32-safe;
  //      softmax is shift-invariant so result is exact-equivalent to reference) ----
  float lrow[4] = {0.f, 0.f, 0.f, 0.f};
  for (int kt = 0; kt < S_; kt += 64) {
#pragma unroll
    for (int c = 0; c < 4; ++c) {
      const bf16_t* kp = &Kh[(size_t)(kt + c * 16 + fr) * HD_ + fg * 8];
      bf16x8 b0 = *(const bf16x8*)kp;
      bf16x8 b1 = *(const bf16x8*)(kp + 32);
      f32x4 zz = {0.f, 0.f, 0.f, 0.f};
      __builtin_amdgcn_s_setprio(1);  // T5: independent-wave regime (m191) — favor MFMA wave
      zz = __builtin_amdgcn_mfma_f32_16x16x32_bf16(aq0, b0, zz, 0, 0, 0);
      zz = __builtin_amdgcn_mfma_f32_16x16x32_bf16(aq1, b1, zz, 0, 0, 0);
      __builtin_amdgcn_s_setprio(0);
#pragma unroll
      for (int j = 0; j < 4; ++j) lrow[j] += __expf(zz[j] * 0.125f);
    }
  }
  // single end-of-pass reduce across the 16 fr lanes (columns split by fr; fg splits k-chunks already summed by MFMA)
  float invl[4];
#pragma unroll
  for (int j = 0; j < 4; ++j) {
    float ps = lrow[j];
#pragma unroll
    for (int mm = 1; mm < 16; mm <<= 1) ps += __shfl_xor(ps, mm, 64);
    invl[j] = 1.f / ps;
  }

  // ---- pass 2: recompute scores, write normalized P (nontemporal), accumulate O = P @ V ----
  f32x4 oacc[4];
#pragma unroll
  for (int g = 0; g < 4; ++g) oacc[g] = (f32x4){0.f, 0.f, 0.f, 0.f};

  float* attn_base = attn + ((size_t)bh * S_ + q0) * S_;
  for (int kt = 0; kt < S_; kt += 64) {
#pragma unroll
    for (int c = 0; c < 4; ++c) {
      const bf16_t* kp = &Kh[(size_t)(kt + c * 16 + fr) * HD_ + fg * 8];
      bf16x8 b0 = *(const bf16x8*)kp;
      bf16x8 b1 = *(const bf16x8*)(kp + 32);
      f32x4 zz = {0.f, 0.f, 0.f, 0.f};
      __builtin_amdgcn_s_setprio(1);
      zz = __builtin_amdgcn_mfma_f32_16x16x32_bf16(aq0, b0, zz, 0, 0, 0);
      zz = __builtin_amdgcn_mfma_f32_16x16x32_bf16(aq1, b1, zz, 0, 0, 0);
      __builtin_amdgcn_s_setprio(0);
#pragma unroll
      for (int j = 0; j < 4; ++j) {
        float p = __expf(zz[j] * 0.125f) * invl[j];
        __builtin_nontemporal_store(p, &attn_base[(size_t)(fg * 4 + j) * S_ + kt + c * 16 + fr]);
        p_lds[w][(fg * 4 + j) * 72 + c * 16 + fr] = (bf16_t)p;
      }
    }
    asm volatile("s_waitcnt lgkmcnt(0)" ::: "memory");
    bf16x8 ap0 = *(const bf16x8*)&p_lds[w][fr * 72 + fg * 8];
    bf16x8 ap1 = *(const bf16x8*)&p_lds[w][fr * 72 + 32 + fg * 8];
#pragma unroll
    for (int g = 0; g < 4; ++g) {
      const bf16_t* vp = &Vh[(size_t)(g * 16 + fr) * S_ + kt + fg * 8];
      bf16x8 b0 = *(const bf16x8*)vp;
      bf16x8 b1 = *(const bf16x8*)(vp + 32);
      __builtin_amdgcn_s_setprio(1);
      oacc[g] = __builtin_amdgcn_mfma_f32_16x16x32_bf16(ap0, b0, oacc[g], 0, 0, 0);
      oacc[g] = __builtin_amdgcn_mfma_f32_16x16x32_bf16(ap1, b1, oacc[g], 0, 0, 0);
      __builtin_amdgcn_s_setprio(0);
    }
  }

  // write O strip into Ob [b][s][h*64+d] (bf16)
#pragma unroll
  for (int g = 0; g < 4; ++g)
#pragma unroll
    for (int j = 0; j < 4; ++j) {
      int s = q0 + fg * 4 + j;
      Ob[((size_t)bb * S_ + s) * D_ + h * HD_ + g * 16 + fr] = (bf16_t)oacc[g][j];
    }
}

// ---------------- launch ----------------
extern "C" void kernel_launch(void* const* d_in, const int* in_sizes, int n_in,
                              void* d_out, int out_size, void* d_ws, size_t ws_size,
                              hipStream_t stream) {
  const float* x  = (const float*)d_in[0];
  const float* wq = (const float*)d_in[1];
  const float* bq = (const float*)d_in[2];
  const float* wk = (const float*)d_in[3];
  const float* bk = (const float*)d_in[4];
  const float* wv = (const float*)d_in[5];
  const float* bv = (const float*)d_in[6];
  const float* wo = (const float*)d_in[7];
  const float* bo = (const float*)d_in[8];

  float* out  = (float*)d_out;
  float* attn = out + (size_t)B_ * S_ * D_;  // outputs concatenated: out, then attn

  char* ws = (char*)d_ws;
  bf16_t* xb  = (bf16_t*)(ws);                      // 8 MiB [4096][1024]
  bf16_t* wqT = (bf16_t*)(ws + (size_t)( 8 << 20)); // 2 MiB each, [N][K]
  bf16_t* wkT = (bf16_t*)(ws + (size_t)(10 << 20));
  bf16_t* wvT = (bf16_t*)(ws + (size_t)(12 << 20));
  bf16_t* woT = (bf16_t*)(ws + (size_t)(14 << 20));
  bf16_t* Qb  = (bf16_t*)(ws + (size_t)(16 << 20)); // 8 MiB [b][h][s][d]
  bf16_t* Kb  = (bf16_t*)(ws + (size_t)(24 << 20)); // 8 MiB [b][h][s][d]
  bf16_t* Vt  = (bf16_t*)(ws + (size_t)(32 << 20)); // 8 MiB [b][h][d][s]
  bf16_t* Ob  = (bf16_t*)(ws + (size_t)(40 << 20)); // 8 MiB [b][s][h*64+d]

  cvt_kernel<<<4096, 256, 0, stream>>>(x, xb);
  transpose_kernel<<<dim3(32, 32, 4), dim3(32, 8), 0, stream>>>(wq, wk, wv, wo, wqT, wkT, wvT, woT);
  qkv_gemm<<<768, 256, 0, stream>>>(xb, wqT, wkT, wvT, bq, bk, bv, Qb, Kb, Vt);
  attn_kernel<<<1024, 256, 0, stream>>>(Qb, Kb, Vt, attn, Ob);
  out_gemm<<<256, 256, 0, stream>>>(Ob, woT, bo, out);
}